// Round 1
// baseline (92.600 us; speedup 1.0000x reference)
//
#include <hip/hip_runtime.h>

#define CC 256
#define CMM 32
#define KW 7
#define KK 49
#define PADW 3
#define HH 56
#define WW 56
#define HP 62
#define LP 3844   // 62*62
#define LL 3136   // 56*56
#define BB 2
#define MM 8
#define MIDW 16

// ---------------- geometry prior: gpk[cm][i][j], 32*49 floats ----------------
__global__ void gpk_kernel(const float* __restrict__ gp_w1, const float* __restrict__ gp_b1,
                           const float* __restrict__ gp_w2, const float* __restrict__ gp_b2,
                           float* __restrict__ gpk) {
  for (int t = threadIdx.x; t < CMM * KK; t += blockDim.x) {
    int c = t / KK, r = t % KK;
    int i = r / KW, j = r % KW;
    float xp_ = (float)(j - PADW);   // x_pos = a[j] = j-3
    float yp_ = (float)(PADW - i);   // y_pos = 3-i
    float acc = gp_b2[c];
    #pragma unroll
    for (int m = 0; m < MIDW; ++m) {
      float h = gp_w1[m * 2 + 0] * xp_ + gp_w1[m * 2 + 1] * yp_ + gp_b1[m];
      h = fmaxf(h, 0.f);
      acc = fmaf(gp_w2[c * MIDW + m], h, acc);
    }
    gpk[t] = acc;
  }
}

// ---------------- k/q 1x1 conv over the PADDED 62x62 grid ----------------
// km/qm at padded-border pixels = bias (conv of zero input), matching reference.
__global__ void kq_kernel(const float* __restrict__ x,
                          const float* __restrict__ k_w, const float* __restrict__ k_b,
                          const float* __restrict__ q_w, const float* __restrict__ q_b,
                          float* __restrict__ km, float* __restrict__ qm) {
  int p = blockIdx.x * 256 + threadIdx.x;
  if (p >= LP) return;
  int b = blockIdx.z;
  int g = blockIdx.y;              // 8 groups of 8 outputs; idx<32 -> k, else q
  int py = p / HP, px = p % HP;
  bool inb = (py >= PADW && py < PADW + HH && px >= PADW && px < PADW + WW);
  int xo = (py - PADW) * WW + (px - PADW);
  const float* xb = x + (size_t)b * CC * LL + (inb ? xo : 0);
  float acc[8];
  #pragma unroll
  for (int u = 0; u < 8; ++u) acc[u] = 0.f;
  const float* w0 = (g < 4) ? (k_w + (g * 8) * CC) : (q_w + (g * 8 - CMM) * CC);
  for (int c = 0; c < CC; ++c) {
    float xv = inb ? xb[(size_t)c * LL] : 0.f;
    #pragma unroll
    for (int u = 0; u < 8; ++u)
      acc[u] = fmaf(w0[u * CC + c], xv, acc[u]);
  }
  #pragma unroll
  for (int u = 0; u < 8; ++u) {
    int idx = g * 8 + u;
    float bias;
    float* dst;
    if (idx < CMM) { bias = k_b[idx]; dst = km + ((size_t)b * CMM + idx) * LP; }
    else           { bias = q_b[idx - CMM]; dst = qm + ((size_t)b * CMM + (idx - CMM)) * LP; }
    dst[p] = acc[u] + bias;
  }
}

// ---------------- fused QK * rowwise-softmax * PV ----------------
// pre[b][m*32+cm][l] = sum_{i} (1/rowsum_i) * sum_j exp(km*qc+gpk - rowmax) * xp
__global__ void attn_kernel(const float* __restrict__ x,
                            const float* __restrict__ km, const float* __restrict__ qm,
                            const float* __restrict__ gpk, float* __restrict__ pre) {
  int l = blockIdx.x * 256 + threadIdx.x;
  int cm = blockIdx.y;
  int b = blockIdx.z;
  if (l >= LL) return;
  int y = l / WW, xc = l % WW;
  const float* kmb = km + ((size_t)b * CMM + cm) * LP;
  float qc = qm[((size_t)b * CMM + cm) * LP + (y + PADW) * HP + (xc + PADW)];
  const float* gp = gpk + cm * KK;
  const float* xb = x + (size_t)b * CC * LL;
  float acc[MM];
  #pragma unroll
  for (int m = 0; m < MM; ++m) acc[m] = 0.f;
  #pragma unroll
  for (int i = 0; i < KW; ++i) {
    int pyy = y + i;                       // padded row
    const float* krow = kmb + pyy * HP + xc;
    float s[KW];
    float mx = -1e30f;
    #pragma unroll
    for (int j = 0; j < KW; ++j) {
      s[j] = fmaf(krow[j], qc, gp[i * KW + j]);
      mx = fmaxf(mx, s[j]);
    }
    float sum = 0.f;
    #pragma unroll
    for (int j = 0; j < KW; ++j) {
      s[j] = __expf(s[j] - mx);
      sum += s[j];
    }
    float inv = 1.f / sum;
    int iy = pyy - PADW;                   // original image row
    if (iy >= 0 && iy < HH) {
      #pragma unroll
      for (int m = 0; m < MM; ++m) {
        const float* xrow = xb + ((size_t)(m * CMM + cm)) * LL + iy * WW;
        float dot = 0.f;
        #pragma unroll
        for (int j = 0; j < KW; ++j) {
          int ix = xc + j - PADW;
          float xv = (ix >= 0 && ix < WW) ? xrow[ix] : 0.f;
          dot = fmaf(s[j], xv, dot);
        }
        acc[m] = fmaf(dot, inv, acc[m]);
      }
    }
  }
  #pragma unroll
  for (int m = 0; m < MM; ++m)
    pre[((size_t)b * CC + (m * CMM + cm)) * LL + l] = acc[m];
}

// ---------------- final 1x1 conv: out = f_w @ pre + f_b ----------------
__global__ void fconv_kernel(const float* __restrict__ pre,
                             const float* __restrict__ f_w, const float* __restrict__ f_b,
                             float* __restrict__ out) {
  int l = blockIdx.x * 256 + threadIdx.x;
  int og = blockIdx.y;    // 32 groups of 8 output channels
  int b = blockIdx.z;
  if (l >= LL) return;
  const float* pb = pre + (size_t)b * CC * LL + l;
  float acc[8];
  #pragma unroll
  for (int u = 0; u < 8; ++u) acc[u] = 0.f;
  const float* w = f_w + (size_t)(og * 8) * CC;
  for (int c = 0; c < CC; ++c) {
    float pv = pb[(size_t)c * LL];
    #pragma unroll
    for (int u = 0; u < 8; ++u)
      acc[u] = fmaf(w[u * CC + c], pv, acc[u]);
  }
  float* ob = out + (size_t)b * CC * LL + l;
  #pragma unroll
  for (int u = 0; u < 8; ++u)
    ob[(size_t)(og * 8 + u) * LL] = acc[u] + f_b[og * 8 + u];
}

extern "C" void kernel_launch(void* const* d_in, const int* in_sizes, int n_in,
                              void* d_out, int out_size, void* d_ws, size_t ws_size,
                              hipStream_t stream) {
  const float* x     = (const float*)d_in[0];
  const float* k_w   = (const float*)d_in[1];
  const float* k_b   = (const float*)d_in[2];
  const float* q_w   = (const float*)d_in[3];
  const float* q_b   = (const float*)d_in[4];
  const float* gp_w1 = (const float*)d_in[5];
  const float* gp_b1 = (const float*)d_in[6];
  const float* gp_w2 = (const float*)d_in[7];
  const float* gp_b2 = (const float*)d_in[8];
  const float* f_w   = (const float*)d_in[9];
  const float* f_b   = (const float*)d_in[10];
  float* out = (float*)d_out;

  float* ws  = (float*)d_ws;
  float* gpk = ws;                       // 1568 floats (pad to 2048)
  float* km  = ws + 2048;                // 2*32*3844
  float* qm  = km + (size_t)BB * CMM * LP;
  float* pre = qm + (size_t)BB * CMM * LP;  // 2*256*3136

  hipLaunchKernelGGL(gpk_kernel, dim3(1), dim3(256), 0, stream,
                     gp_w1, gp_b1, gp_w2, gp_b2, gpk);
  hipLaunchKernelGGL(kq_kernel, dim3((LP + 255) / 256, 8, BB), dim3(256), 0, stream,
                     x, k_w, k_b, q_w, q_b, km, qm);
  hipLaunchKernelGGL(attn_kernel, dim3((LL + 255) / 256, CMM, BB), dim3(256), 0, stream,
                     x, km, qm, gpk, pre);
  hipLaunchKernelGGL(fconv_kernel, dim3((LL + 255) / 256, CC / 8, BB), dim3(256), 0, stream,
                     pre, f_w, f_b, out);
}